// Round 1
// baseline (2141.534 us; speedup 1.0000x reference)
//
#include <hip/hip_runtime.h>
#include <math.h>

constexpr int CH   = 128;      // CH_IN == CH_LAT == CLASSES
constexpr int WW   = 131072;   // W
constexpr int NB   = 4;        // B
constexpr int NPIX = NB * WW;  // 524288
constexpr int TPB  = 256;

// Fused: conv1(1x1) -> BN -> LeakyReLU -> conv2(1x1, 129 rows) -> argmax ->
//        gather cm_w row -> reg dot -> (out, mask)
__global__ __launch_bounds__(TPB, 2) void fused_seg_kernel(
    const float* __restrict__ x,     // (B,128,1,W)
    const float* __restrict__ w1,    // (128,128) row-major [o][c]
    const float* __restrict__ b1,    // (128)
    const float* __restrict__ gamma,
    const float* __restrict__ beta,
    const float* __restrict__ mean,
    const float* __restrict__ var,
    const float* __restrict__ w2,    // (129,128) row-major [o][c]
    const float* __restrict__ b2,    // (129)
    const float* __restrict__ cmw,   // (128,128)
    const float* __restrict__ cmb,   // (128)
    float* __restrict__ out)         // [0,NPIX): reg-out, [NPIX,2*NPIX): mask
{
    __shared__ float lds_w[CH * CH];      // 64KB: phase1 = w1^T [c][o], phase2 = w2 rows 0..127 [r][c]
    __shared__ float lds_A[CH];           // BN scale
    __shared__ float lds_C[CH];           // BN offset (bias folded)
    __shared__ float lds_b2[CH + 1];
    __shared__ float lds_w2last[CH];      // w2 row 128 (mask row)
    __shared__ float lds_cmb[CH];

    const int tid = threadIdx.x;
    const int p   = blockIdx.x * TPB + tid;   // pixel index: p = b*W + w
    const int b   = p >> 17;                  // / W
    const int w   = p & (WW - 1);

    // ---- phase 0: stage constants + w1^T ----
    if (tid < CH) {
        float s = gamma[tid] / sqrtf(var[tid] + 1e-5f);
        lds_A[tid] = s;
        lds_C[tid] = (b1[tid] - mean[tid]) * s + beta[tid];
        lds_w2last[tid] = w2[CH * CH + tid];
        lds_cmb[tid] = cmb[tid];
    }
    if (tid < CH + 1) lds_b2[tid] = b2[tid];

    {
        // thread t covers output-channel o = t&127; two threads per o split c-range.
        // LDS write bank = o%32 -> consecutive lanes hit distinct banks (conflict-free).
        const int o    = tid & 127;
        const int half = tid >> 7;
        #pragma unroll
        for (int k = 0; k < 16; ++k) {
            const int c = k * 8 + half * 4;
            float4 v = *(const float4*)&w1[o * CH + c];
            lds_w[(c + 0) * CH + o] = v.x;
            lds_w[(c + 1) * CH + o] = v.y;
            lds_w[(c + 2) * CH + o] = v.z;
            lds_w[(c + 3) * CH + o] = v.w;
        }
    }
    __syncthreads();

    // ---- GEMM1: acc[o] = sum_c x[b,c,w] * w1[o][c] ----
    float acc[CH];
    #pragma unroll
    for (int o = 0; o < CH; ++o) acc[o] = 0.f;

    const float* xp = x + ((size_t)b * CH) * WW + w;
    for (int cg = 0; cg < CH; cg += 4) {
        const float xv0 = xp[(size_t)(cg + 0) * WW];
        const float xv1 = xp[(size_t)(cg + 1) * WW];
        const float xv2 = xp[(size_t)(cg + 2) * WW];
        const float xv3 = xp[(size_t)(cg + 3) * WW];
        #pragma unroll
        for (int o4 = 0; o4 < CH / 4; ++o4) {
            float4 a0 = *(const float4*)&lds_w[(cg + 0) * CH + o4 * 4];
            float4 a1 = *(const float4*)&lds_w[(cg + 1) * CH + o4 * 4];
            float4 a2 = *(const float4*)&lds_w[(cg + 2) * CH + o4 * 4];
            float4 a3 = *(const float4*)&lds_w[(cg + 3) * CH + o4 * 4];
            acc[o4*4+0] += xv0 * a0.x; acc[o4*4+1] += xv0 * a0.y;
            acc[o4*4+2] += xv0 * a0.z; acc[o4*4+3] += xv0 * a0.w;
            acc[o4*4+0] += xv1 * a1.x; acc[o4*4+1] += xv1 * a1.y;
            acc[o4*4+2] += xv1 * a1.z; acc[o4*4+3] += xv1 * a1.w;
            acc[o4*4+0] += xv2 * a2.x; acc[o4*4+1] += xv2 * a2.y;
            acc[o4*4+2] += xv2 * a2.z; acc[o4*4+3] += xv2 * a2.w;
            acc[o4*4+0] += xv3 * a3.x; acc[o4*4+1] += xv3 * a3.y;
            acc[o4*4+2] += xv3 * a3.z; acc[o4*4+3] += xv3 * a3.w;
        }
    }

    // ---- BN + LeakyReLU (post-scale matches reference order) ----
    #pragma unroll
    for (int o = 0; o < CH; ++o) {
        float v = acc[o] * lds_A[o] + lds_C[o];
        acc[o]  = (v >= 0.f) ? v : 0.01f * v;
    }

    // ---- re-stage LDS with w2 rows 0..127 ----
    __syncthreads();
    #pragma unroll
    for (int k = 0; k < (CH * CH) / (TPB * 4); ++k) {   // 16 iters
        const int i = (k * TPB + tid) * 4;
        *(float4*)&lds_w[i] = *(const float4*)&w2[i];
    }
    __syncthreads();

    // ---- GEMM2 (class logits) + running argmax (strict >, first-index ties) ----
    float best = -3.0e38f;
    int   bidx = 0;
    for (int rg = 0; rg < 16; ++rg) {
        float y[8];
        #pragma unroll
        for (int j = 0; j < 8; ++j) y[j] = lds_b2[rg * 8 + j];
        const int base = rg * 8 * CH;
        #pragma unroll
        for (int c4 = 0; c4 < 32; ++c4) {
            #pragma unroll
            for (int j = 0; j < 8; ++j) {
                float4 wv = *(const float4*)&lds_w[base + j * CH + c4 * 4];
                y[j] += acc[c4*4+0] * wv.x;
                y[j] += acc[c4*4+1] * wv.y;
                y[j] += acc[c4*4+2] * wv.z;
                y[j] += acc[c4*4+3] * wv.w;
            }
        }
        #pragma unroll
        for (int j = 0; j < 8; ++j) {
            if (y[j] > best) { best = y[j]; bidx = rg * 8 + j; }
        }
    }

    // ---- mask row (w2 row 128) ----
    float m0 = 0.f, m1 = 0.f, m2 = 0.f, m3 = 0.f;
    #pragma unroll
    for (int i = 0; i < 32; ++i) {
        m0 += acc[i*4+0] * lds_w2last[i*4+0];
        m1 += acc[i*4+1] * lds_w2last[i*4+1];
        m2 += acc[i*4+2] * lds_w2last[i*4+2];
        m3 += acc[i*4+3] * lds_w2last[i*4+3];
    }
    const float mv   = ((m0 + m1) + (m2 + m3)) + lds_b2[CH];
    const float mask = (mv >= 0.f) ? mv : 0.01f * mv;

    // ---- cm gather + reg dot ----
    const float4* cmrow = (const float4*)(cmw + (size_t)bidx * CH);
    float r0 = 0.f, r1 = 0.f, r2 = 0.f, r3 = 0.f;
    #pragma unroll
    for (int i = 0; i < 32; ++i) {
        float4 v = cmrow[i];
        r0 += acc[i*4+0] * v.x;
        r1 += acc[i*4+1] * v.y;
        r2 += acc[i*4+2] * v.z;
        r3 += acc[i*4+3] * v.w;
    }
    const float reg = ((r0 + r1) + (r2 + r3)) + lds_cmb[bidx];

    out[p]        = ((float)bidx + reg) * (1.0f / 128.0f);
    out[NPIX + p] = mask;
}

extern "C" void kernel_launch(void* const* d_in, const int* in_sizes, int n_in,
                              void* d_out, int out_size, void* d_ws, size_t ws_size,
                              hipStream_t stream) {
    const float* x     = (const float*)d_in[0];
    const float* w1    = (const float*)d_in[1];
    const float* b1    = (const float*)d_in[2];
    const float* gamma = (const float*)d_in[3];
    const float* beta  = (const float*)d_in[4];
    const float* mean  = (const float*)d_in[5];
    const float* var   = (const float*)d_in[6];
    const float* w2    = (const float*)d_in[7];
    const float* b2    = (const float*)d_in[8];
    const float* cmw   = (const float*)d_in[9];
    const float* cmb   = (const float*)d_in[10];
    float* out = (float*)d_out;

    dim3 grid(NPIX / TPB);
    hipLaunchKernelGGL(fused_seg_kernel, grid, dim3(TPB), 0, stream,
                       x, w1, b1, gamma, beta, mean, var, w2, b2, cmw, cmb, out);
}